// Round 1
// baseline (10909.927 us; speedup 1.0000x reference)
//
#include <hip/hip_runtime.h>

#define BATCH 16
#define SLEN 256
#define HID 512
#define EMB 768
#define VOC 30522
#define TDEC 99
#define ENC_BLOCKS 128
#define DEC_BLOCKS 64

__device__ __forceinline__ float sigmoidf_(float x) { return 1.f / (1.f + expf(-x)); }

// ---------------- generic tiled fp32 GEMM: C = A @ W^T (+bias/base) ----------------
// A: M x K (row-major, lda). W: N x K (row-major, ldb).
// gather: if ids != null, A-row for m is emb row ids[(m%16)*100 + (m/16)]
// out_mode 0: out[m*N+n] = acc + bias[n]
// out_mode 1: b=m%16, t=m/16: out[b*TDEC*N + t*N + n] = acc + base[b*N+n]
__global__ __launch_bounds__(256) void gemm_k(
    const float* __restrict__ A, int lda,
    const float* __restrict__ W, int ldb,
    const float* __restrict__ bias,
    const float* __restrict__ base,
    float* __restrict__ out,
    int M, int N, int K,
    const int* __restrict__ ids,
    int out_mode)
{
    __shared__ float As[16][64];
    __shared__ float Bs[16][64];
    const int tid = threadIdx.x;
    const int m0 = blockIdx.y * 64, n0 = blockIdx.x * 64;
    const int la_m = tid >> 2, la_k = (tid & 3) << 2;   // A tile loader: 64 rows x 16 k
    const int lb_n = la_m,    lb_k = la_k;              // B tile loader: 64 n x 16 k
    const int tx = tid & 15, ty = tid >> 4;             // compute: 4x4 micro-tile

    const int gm = m0 + la_m;
    const bool a_ok = gm < M;
    const float* Ap = A;
    if (a_ok) {
        int r = gm;
        if (ids) r = ids[(gm & 15) * 100 + (gm >> 4)];
        Ap = A + (size_t)r * lda;
    }
    const int gn = n0 + lb_n;
    const bool b_ok = gn < N;
    const float* Wp = b_ok ? (W + (size_t)gn * ldb) : W;

    float acc[4][4] = {};
    for (int k0 = 0; k0 < K; k0 += 16) {
        float4 av = make_float4(0.f, 0.f, 0.f, 0.f);
        float4 bv = make_float4(0.f, 0.f, 0.f, 0.f);
        if (a_ok) av = *(const float4*)(Ap + k0 + la_k);
        if (b_ok) bv = *(const float4*)(Wp + k0 + lb_k);
        __syncthreads();
        As[la_k + 0][la_m] = av.x; As[la_k + 1][la_m] = av.y;
        As[la_k + 2][la_m] = av.z; As[la_k + 3][la_m] = av.w;
        Bs[lb_k + 0][lb_n] = bv.x; Bs[lb_k + 1][lb_n] = bv.y;
        Bs[lb_k + 2][lb_n] = bv.z; Bs[lb_k + 3][lb_n] = bv.w;
        __syncthreads();
        #pragma unroll
        for (int kk = 0; kk < 16; ++kk) {
            float4 a = *(const float4*)&As[kk][ty << 2];
            float4 b = *(const float4*)&Bs[kk][tx << 2];
            float a4[4] = {a.x, a.y, a.z, a.w};
            float b4[4] = {b.x, b.y, b.z, b.w};
            #pragma unroll
            for (int i = 0; i < 4; ++i)
                #pragma unroll
                for (int jj = 0; jj < 4; ++jj)
                    acc[i][jj] = fmaf(a4[i], b4[jj], acc[i][jj]);
        }
    }
    #pragma unroll
    for (int i = 0; i < 4; ++i) {
        const int m = m0 + (ty << 2) + i;
        if (m >= M) continue;
        #pragma unroll
        for (int jj = 0; jj < 4; ++jj) {
            const int n = n0 + (tx << 2) + jj;
            if (n >= N) continue;
            float v = acc[i][jj];
            if (out_mode == 0) {
                if (bias) v += bias[n];
                out[(size_t)m * N + n] = v;
            } else {
                const int b = m & 15, t = m >> 4;
                out[(size_t)b * ((size_t)TDEC * N) + (size_t)t * N + n] = v + base[(size_t)b * N + n];
            }
        }
    }
}

// ------------- device-wide step barrier (monotonic counter, agent scope) -------------
__device__ __forceinline__ void step_barrier(unsigned* bar, unsigned target)
{
    __threadfence();
    __syncthreads();
    if (threadIdx.x == 0) {
        __hip_atomic_fetch_add(bar, 1u, __ATOMIC_ACQ_REL, __HIP_MEMORY_SCOPE_AGENT);
        while (__hip_atomic_load(bar, __ATOMIC_ACQUIRE, __HIP_MEMORY_SCOPE_AGENT) < target)
            __builtin_amdgcn_s_sleep(2);
    }
    __syncthreads();
}

// ---------------- persistent bidirectional encoder GRU recurrence ----------------
// 128 blocks: blocks [0,64) = forward, [64,128) = backward. Each block owns 8 hidden
// units (24 Whh rows) with weights in VGPRs (interleaved k: thread seg handles k = seg+16i).
__global__ __launch_bounds__(256) void enc_rec_kernel(
    const float* __restrict__ gi_f, const float* __restrict__ gi_b,
    const float* __restrict__ Whh_f, const float* __restrict__ Whh_b,
    const float* __restrict__ bhh_f, const float* __restrict__ bhh_b,
    float* __restrict__ enc_out,   // [16][256][1024]
    float* __restrict__ h_buf,     // [2 parity][2 dir][16][512]
    unsigned* __restrict__ bar)
{
    const int dir  = blockIdx.x >> 6;
    const int ublk = blockIdx.x & 63;
    const float* gi  = dir ? gi_b  : gi_f;
    const float* Whh = dir ? Whh_b : Whh_f;
    const float* bhh = dir ? bhh_b : bhh_f;
    const int tid = threadIdx.x;
    const int u   = tid >> 5;        // 0..7 unit within block
    const int bh  = (tid >> 4) & 1;  // batch half
    const int seg = tid & 15;        // k segment
    const int j   = ublk * 8 + u;    // global hidden unit

    float w0[32], w1[32], w2[32];
    #pragma unroll
    for (int i = 0; i < 32; ++i) {
        const int k = seg + (i << 4);
        w0[i] = Whh[(size_t)(0 * HID + j) * HID + k];
        w1[i] = Whh[(size_t)(1 * HID + j) * HID + k];
        w2[i] = Whh[(size_t)(2 * HID + j) * HID + k];
    }
    __shared__ float hs[BATCH * HID];
    __shared__ float red[8][16][3];

    float* hb = h_buf + dir * (BATCH * HID);
    const int PST = 2 * BATCH * HID;

    for (int s = 0; s < SLEN; ++s) {
        const int par = s & 1;
        const int s_eff = dir ? (SLEN - 1 - s) : s;
        const float* hsrc = hb + par * PST;
        for (int i = tid; i < BATCH * HID; i += 256)
            hs[i] = __hip_atomic_load(hsrc + i, __ATOMIC_RELAXED, __HIP_MEMORY_SCOPE_AGENT);
        __syncthreads();

        float a0[8] = {}, a1[8] = {}, a2[8] = {};
        #pragma unroll
        for (int i = 0; i < 32; ++i) {
            const int k = seg + (i << 4);
            const float* hp = hs + bh * (8 * HID) + k;
            #pragma unroll
            for (int b2 = 0; b2 < 8; ++b2) {
                const float hv = hp[b2 * HID];
                a0[b2] = fmaf(w0[i], hv, a0[b2]);
                a1[b2] = fmaf(w1[i], hv, a1[b2]);
                a2[b2] = fmaf(w2[i], hv, a2[b2]);
            }
        }
        #pragma unroll
        for (int off = 1; off < 16; off <<= 1) {
            #pragma unroll
            for (int b2 = 0; b2 < 8; ++b2) {
                a0[b2] += __shfl_xor(a0[b2], off, 64);
                a1[b2] += __shfl_xor(a1[b2], off, 64);
                a2[b2] += __shfl_xor(a2[b2], off, 64);
            }
        }
        if (seg == 0) {
            #pragma unroll
            for (int b2 = 0; b2 < 8; ++b2) {
                const int b = bh * 8 + b2;
                red[u][b][0] = a0[b2];
                red[u][b][1] = a1[b2];
                red[u][b][2] = a2[b2];
            }
        }
        __syncthreads();
        if (tid < 128) {
            const int u2 = tid >> 4, b = tid & 15;
            const int jj = ublk * 8 + u2;
            const float ghr = red[u2][b][0] + bhh[jj];
            const float ghz = red[u2][b][1] + bhh[HID + jj];
            const float ghn = red[u2][b][2] + bhh[2 * HID + jj];
            const float* gp = gi + (size_t)(b * SLEN + s_eff) * 1536;
            const float r = sigmoidf_(gp[jj] + ghr);
            const float z = sigmoidf_(gp[HID + jj] + ghz);
            const float n = tanhf(gp[2 * HID + jj] + r * ghn);
            const float hnew = (1.f - z) * n + z * hs[b * HID + jj];
            enc_out[(size_t)(b * SLEN + s_eff) * 1024 + dir * HID + jj] = hnew;
            __hip_atomic_store(hb + (par ^ 1) * PST + b * HID + jj, hnew,
                               __ATOMIC_RELAXED, __HIP_MEMORY_SCOPE_AGENT);
        }
        step_barrier(bar, (unsigned)ENC_BLOCKS * (unsigned)(s + 1));
    }
}

// ---------------- persistent decoder GRU recurrence (64 blocks) ----------------
__global__ __launch_bounds__(256) void dec_rec_kernel(
    const float* __restrict__ gi_x,   // [99*16][1536] (includes dec_bih), m = t*16+b
    const float* __restrict__ gi_ctx, // [16][1536]
    const float* __restrict__ Whh, const float* __restrict__ bhh,
    const float* __restrict__ h_init, // [16][512]
    float* __restrict__ h_all,        // [99][16][512]
    unsigned* __restrict__ bar)
{
    const int ublk = blockIdx.x;
    const int tid = threadIdx.x;
    const int u   = tid >> 5;
    const int bh  = (tid >> 4) & 1;
    const int seg = tid & 15;
    const int j   = ublk * 8 + u;

    float w0[32], w1[32], w2[32];
    #pragma unroll
    for (int i = 0; i < 32; ++i) {
        const int k = seg + (i << 4);
        w0[i] = Whh[(size_t)(0 * HID + j) * HID + k];
        w1[i] = Whh[(size_t)(1 * HID + j) * HID + k];
        w2[i] = Whh[(size_t)(2 * HID + j) * HID + k];
    }
    __shared__ float hs[BATCH * HID];
    __shared__ float red[8][16][3];

    for (int t = 0; t < TDEC; ++t) {
        const float* hsrc = (t == 0) ? h_init : (h_all + (size_t)(t - 1) * (BATCH * HID));
        for (int i = tid; i < BATCH * HID; i += 256)
            hs[i] = __hip_atomic_load(hsrc + i, __ATOMIC_RELAXED, __HIP_MEMORY_SCOPE_AGENT);
        __syncthreads();

        float a0[8] = {}, a1[8] = {}, a2[8] = {};
        #pragma unroll
        for (int i = 0; i < 32; ++i) {
            const int k = seg + (i << 4);
            const float* hp = hs + bh * (8 * HID) + k;
            #pragma unroll
            for (int b2 = 0; b2 < 8; ++b2) {
                const float hv = hp[b2 * HID];
                a0[b2] = fmaf(w0[i], hv, a0[b2]);
                a1[b2] = fmaf(w1[i], hv, a1[b2]);
                a2[b2] = fmaf(w2[i], hv, a2[b2]);
            }
        }
        #pragma unroll
        for (int off = 1; off < 16; off <<= 1) {
            #pragma unroll
            for (int b2 = 0; b2 < 8; ++b2) {
                a0[b2] += __shfl_xor(a0[b2], off, 64);
                a1[b2] += __shfl_xor(a1[b2], off, 64);
                a2[b2] += __shfl_xor(a2[b2], off, 64);
            }
        }
        if (seg == 0) {
            #pragma unroll
            for (int b2 = 0; b2 < 8; ++b2) {
                const int b = bh * 8 + b2;
                red[u][b][0] = a0[b2];
                red[u][b][1] = a1[b2];
                red[u][b][2] = a2[b2];
            }
        }
        __syncthreads();
        if (tid < 128) {
            const int u2 = tid >> 4, b = tid & 15;
            const int jj = ublk * 8 + u2;
            const float ghr = red[u2][b][0] + bhh[jj];
            const float ghz = red[u2][b][1] + bhh[HID + jj];
            const float ghn = red[u2][b][2] + bhh[2 * HID + jj];
            const float* gxp = gi_x + (size_t)(t * BATCH + b) * 1536;
            const float* gcp = gi_ctx + (size_t)b * 1536;
            const float r = sigmoidf_(gxp[jj] + gcp[jj] + ghr);
            const float z = sigmoidf_(gxp[HID + jj] + gcp[HID + jj] + ghz);
            const float n = tanhf(gxp[2 * HID + jj] + gcp[2 * HID + jj] + r * ghn);
            const float hnew = (1.f - z) * n + z * hs[b * HID + jj];
            __hip_atomic_store(h_all + (size_t)t * (BATCH * HID) + b * HID + jj, hnew,
                               __ATOMIC_RELAXED, __HIP_MEMORY_SCOPE_AGENT);
        }
        step_barrier(bar, (unsigned)DEC_BLOCKS * (unsigned)(t + 1));
    }
}

// ---------------- attention precompute kernels ----------------
// cw[m] = sum_j comb_W[j] * attn_W[j, m], m < 1024  (enc_out part of the score;
// the h-dependent part is constant across s and cancels in softmax)
__global__ __launch_bounds__(256) void cw_kernel(const float* __restrict__ attnW,
                                                 const float* __restrict__ combW,
                                                 float* __restrict__ cw)
{
    const int m = blockIdx.x * 256 + threadIdx.x;
    if (m < 1024) {
        float s = 0.f;
        for (int jj = 0; jj < HID; ++jj)
            s = fmaf(combW[jj], attnW[(size_t)jj * 1536 + m], s);
        cw[m] = s;
    }
}

__global__ __launch_bounds__(256) void score_kernel(const float* __restrict__ enc_out,
                                                    const float* __restrict__ cw,
                                                    float* __restrict__ score)
{
    const int g = blockIdx.x * 256 + threadIdx.x;
    const int wv = g >> 6, lane = g & 63;   // wv = b*256+s, 4096 waves total
    const float* e = enc_out + (size_t)wv * 1024;
    float s = 0.f;
    #pragma unroll
    for (int i = 0; i < 16; ++i) {
        const int idx = i * 64 + lane;
        s = fmaf(cw[idx], e[idx], s);
    }
    #pragma unroll
    for (int off = 32; off; off >>= 1) s += __shfl_xor(s, off, 64);
    if (lane == 0) score[wv] = s;
}

__global__ __launch_bounds__(256) void attn_kernel(const float* __restrict__ enc_out,
                                                   const float* __restrict__ score,
                                                   const int* __restrict__ mask,
                                                   float* __restrict__ ctx0,
                                                   float* __restrict__ validv)
{
    const int b = blockIdx.x, t = threadIdx.x;   // t = s position, block = batch
    __shared__ float wsm[SLEN];
    __shared__ float rb[32];
    const int mk = mask[b * SLEN + t];
    const float sc = (mk > 0) ? score[b * SLEN + t] : -1e9f;
    float mx = sc;
    #pragma unroll
    for (int off = 32; off; off >>= 1) mx = fmaxf(mx, __shfl_xor(mx, off, 64));
    if ((t & 63) == 0) rb[t >> 6] = mx;
    __syncthreads();
    const float m4 = fmaxf(fmaxf(rb[0], rb[1]), fmaxf(rb[2], rb[3]));
    const float e = expf(sc - m4);   // masked: exp(-1e9-...) underflows to exactly 0
    float sm = e;
    #pragma unroll
    for (int off = 32; off; off >>= 1) sm += __shfl_xor(sm, off, 64);
    if ((t & 63) == 0) rb[8 + (t >> 6)] = sm;
    float vm = (float)mk;
    #pragma unroll
    for (int off = 32; off; off >>= 1) vm += __shfl_xor(vm, off, 64);
    if ((t & 63) == 0) rb[16 + (t >> 6)] = vm;
    __syncthreads();
    const float tot = rb[8] + rb[9] + rb[10] + rb[11];
    wsm[t] = e / tot;
    if (t == 0) validv[b] = rb[16] + rb[17] + rb[18] + rb[19];
    __syncthreads();
    for (int d = t; d < 1024; d += 256) {
        float acc = 0.f;
        for (int s = 0; s < SLEN; ++s)
            acc = fmaf(wsm[s], enc_out[(size_t)(b * SLEN + s) * 1024 + d], acc);
        ctx0[b * 1024 + d] = acc;
    }
}

__global__ __launch_bounds__(256) void hinit_kernel(const float* __restrict__ enc_out,
                                                    float* __restrict__ h_init)
{
    const int i = blockIdx.x * 256 + threadIdx.x;  // 0..8191
    const int b = i >> 9, jj = i & 511;
    h_init[i] = enc_out[(size_t)(b * SLEN + (SLEN - 1)) * 1024 + jj]
              + enc_out[(size_t)(b * SLEN + 0) * 1024 + HID + jj];
}

__global__ __launch_bounds__(256) void ctxp_kernel(const float* __restrict__ ctx0,
                                                   const float* __restrict__ projW,
                                                   const float* __restrict__ projb,
                                                   const float* __restrict__ validv,
                                                   float* __restrict__ ctxp)
{
    const int i = blockIdx.x * 256 + threadIdx.x;  // 0..8191: b*512+n
    const int b = i >> 9, n = i & 511;
    const float* c = ctx0 + (size_t)b * 1024;
    const float* w = projW + (size_t)n * 1024;
    float s = projb[n];
    for (int k = 0; k < 1024; k += 4) {
        const float4 cv = *(const float4*)(c + k);
        const float4 wv = *(const float4*)(w + k);
        s = fmaf(cv.x, wv.x, s); s = fmaf(cv.y, wv.y, s);
        s = fmaf(cv.z, wv.z, s); s = fmaf(cv.w, wv.w, s);
    }
    ctxp[i] = (validv[b] > 0.f) ? s : 0.f;
}

__global__ __launch_bounds__(256) void gictx_kernel(const float* __restrict__ ctxp,
                                                    const float* __restrict__ dWih,
                                                    float* __restrict__ gi_ctx)
{
    const int i = blockIdx.x * 256 + threadIdx.x;  // 0..24575: b*1536+r
    const int b = i / 1536, r = i % 1536;
    const float* c = ctxp + (size_t)b * HID;
    const float* w = dWih + (size_t)r * 1280 + 768;  // ctx columns of dec_Wih
    float s = 0.f;
    for (int k = 0; k < HID; k += 4) {
        const float4 cv = *(const float4*)(c + k);
        const float4 wv = *(const float4*)(w + k);
        s = fmaf(cv.x, wv.x, s); s = fmaf(cv.y, wv.y, s);
        s = fmaf(cv.z, wv.z, s); s = fmaf(cv.w, wv.w, s);
    }
    gi_ctx[i] = s;
}

extern "C" void kernel_launch(void* const* d_in, const int* in_sizes, int n_in,
                              void* d_out, int out_size, void* d_ws, size_t ws_size,
                              hipStream_t stream)
{
    const float* bert  = (const float*)d_in[0];
    const int*   amask = (const int*)d_in[1];
    const int*   ids   = (const int*)d_in[2];
    const float* emb   = (const float*)d_in[3];
    const float* eWihf = (const float*)d_in[4];
    const float* eWhhf = (const float*)d_in[5];
    const float* ebihf = (const float*)d_in[6];
    const float* ebhhf = (const float*)d_in[7];
    const float* eWihb = (const float*)d_in[8];
    const float* eWhhb = (const float*)d_in[9];
    const float* ebihb = (const float*)d_in[10];
    const float* ebhhb = (const float*)d_in[11];
    const float* dWih  = (const float*)d_in[12];
    const float* dWhh  = (const float*)d_in[13];
    const float* dbih  = (const float*)d_in[14];
    const float* dbhh  = (const float*)d_in[15];
    const float* attnW = (const float*)d_in[16];
    const float* combW = (const float*)d_in[18];
    const float* projW = (const float*)d_in[20];
    const float* projb = (const float*)d_in[21];
    const float* outW  = (const float*)d_in[22];
    const float* outb  = (const float*)d_in[23];
    float* out = (float*)d_out;

    float* ws = (float*)d_ws;
    size_t off = 0;
    auto alloc = [&](size_t n) { float* p = ws + off; off += (n + 255) & ~(size_t)255; return p; };
    float* h_buf   = alloc(2 * 2 * BATCH * HID);          // 32768 (must be first, memset)
    float* barf    = alloc(256);                          // barrier counters
    unsigned* bar  = (unsigned*)barf;
    float* cw      = alloc(1024);
    float* score   = alloc(BATCH * SLEN);
    float* validv  = alloc(BATCH);
    float* ctx0    = alloc(BATCH * 1024);
    float* ctxp    = alloc(BATCH * HID);
    float* h_init  = alloc(BATCH * HID);
    float* gi_ctx  = alloc(BATCH * 1536);
    float* gi_f    = alloc((size_t)BATCH * SLEN * 1536);
    float* gi_b    = alloc((size_t)BATCH * SLEN * 1536);
    float* enc_out = alloc((size_t)BATCH * SLEN * 1024);
    float* gi_x    = alloc((size_t)TDEC * BATCH * 1536);
    float* basel   = alloc((size_t)BATCH * VOC);
    float* h_all   = alloc((size_t)TDEC * BATCH * HID);

    // zero h0 and barrier counters (ws is poisoned 0xAA before every launch)
    hipMemsetAsync(h_buf, 0, (2 * 2 * BATCH * HID + 256) * sizeof(float), stream);

    const dim3 blk(256);
    // encoder input projections gi = x @ Wih^T + bih, layout [b][s][1536]
    gemm_k<<<dim3(1536 / 64, (BATCH * SLEN) / 64), blk, 0, stream>>>(
        bert, EMB, eWihf, EMB, ebihf, nullptr, gi_f, BATCH * SLEN, 1536, EMB, nullptr, 0);
    gemm_k<<<dim3(1536 / 64, (BATCH * SLEN) / 64), blk, 0, stream>>>(
        bert, EMB, eWihb, EMB, ebihb, nullptr, gi_b, BATCH * SLEN, 1536, EMB, nullptr, 0);
    cw_kernel<<<4, blk, 0, stream>>>(attnW, combW, cw);
    // bidirectional recurrence
    enc_rec_kernel<<<ENC_BLOCKS, blk, 0, stream>>>(gi_f, gi_b, eWhhf, eWhhb, ebhhf, ebhhb,
                                                   enc_out, h_buf, bar);
    // attention (h-independent): scores -> softmax -> ctx -> proj
    score_kernel<<<1024, blk, 0, stream>>>(enc_out, cw, score);
    attn_kernel<<<BATCH, blk, 0, stream>>>(enc_out, score, amask, ctx0, validv);
    hinit_kernel<<<32, blk, 0, stream>>>(enc_out, h_init);
    ctxp_kernel<<<32, blk, 0, stream>>>(ctx0, projW, projb, validv, ctxp);
    gictx_kernel<<<96, blk, 0, stream>>>(ctxp, dWih, gi_ctx);
    // token-embedding projection (gather GEMM), m = t*16+b
    gemm_k<<<dim3(1536 / 64, (TDEC * BATCH + 63) / 64), blk, 0, stream>>>(
        emb, EMB, dWih, 1280, dbih, nullptr, gi_x, TDEC * BATCH, 1536, EMB, ids, 0);
    // base logits = ctxp @ outW[:,512:]^T + out_b
    gemm_k<<<dim3((VOC + 63) / 64, 1), blk, 0, stream>>>(
        ctxp, HID, outW + HID, 1024, outb, nullptr, basel, BATCH, VOC, HID, nullptr, 0);
    // decoder recurrence -> h_all
    dec_rec_kernel<<<DEC_BLOCKS, blk, 0, stream>>>(gi_x, gi_ctx, dWhh, dbhh, h_init, h_all, bar + 1);
    // final logits = h_all @ outW[:,0:512]^T + base, scattered to [b][t][v]
    gemm_k<<<dim3((VOC + 63) / 64, (TDEC * BATCH + 63) / 64), blk, 0, stream>>>(
        h_all, HID, outW, 1024, nullptr, basel, out, TDEC * BATCH, VOC, HID, nullptr, 1);
}

// Round 2
// 6905.714 us; speedup vs baseline: 1.5798x; 1.5798x over previous
//
#include <hip/hip_runtime.h>

#define BATCH 16
#define SLEN 256
#define HID 512
#define EMB 768
#define VOC 30522
#define TDEC 99
#define ENC_BLOCKS 128
#define DEC_BLOCKS 64

__device__ __forceinline__ float sigmoidf_(float x) { return 1.f / (1.f + expf(-x)); }

// ---------------- generic tiled fp32 GEMM: C = A @ W^T (+bias/base) ----------------
// A: M x K (row-major, lda). W: N x K (row-major, ldb).
// gather: if ids != null, A-row for m is emb row ids[(m%16)*100 + (m/16)]
// out_mode 0: out[m*N+n] = acc + bias[n]
// out_mode 1: b=m%16, t=m/16: out[b*TDEC*N + t*N + n] = acc + base[b*N+n]
__global__ __launch_bounds__(256) void gemm_k(
    const float* __restrict__ A, int lda,
    const float* __restrict__ W, int ldb,
    const float* __restrict__ bias,
    const float* __restrict__ base,
    float* __restrict__ out,
    int M, int N, int K,
    const int* __restrict__ ids,
    int out_mode)
{
    __shared__ float As[16][64];
    __shared__ float Bs[16][64];
    const int tid = threadIdx.x;
    const int m0 = blockIdx.y * 64, n0 = blockIdx.x * 64;
    const int la_m = tid >> 2, la_k = (tid & 3) << 2;   // A tile loader: 64 rows x 16 k
    const int lb_n = la_m,    lb_k = la_k;              // B tile loader: 64 n x 16 k
    const int tx = tid & 15, ty = tid >> 4;             // compute: 4x4 micro-tile

    const int gm = m0 + la_m;
    const bool a_ok = gm < M;
    const float* Ap = A;
    if (a_ok) {
        int r = gm;
        if (ids) r = ids[(gm & 15) * 100 + (gm >> 4)];
        Ap = A + (size_t)r * lda;
    }
    const int gn = n0 + lb_n;
    const bool b_ok = gn < N;
    const float* Wp = b_ok ? (W + (size_t)gn * ldb) : W;

    float acc[4][4] = {};
    for (int k0 = 0; k0 < K; k0 += 16) {
        float4 av = make_float4(0.f, 0.f, 0.f, 0.f);
        float4 bv = make_float4(0.f, 0.f, 0.f, 0.f);
        if (a_ok) av = *(const float4*)(Ap + k0 + la_k);
        if (b_ok) bv = *(const float4*)(Wp + k0 + lb_k);
        __syncthreads();
        As[la_k + 0][la_m] = av.x; As[la_k + 1][la_m] = av.y;
        As[la_k + 2][la_m] = av.z; As[la_k + 3][la_m] = av.w;
        Bs[lb_k + 0][lb_n] = bv.x; Bs[lb_k + 1][lb_n] = bv.y;
        Bs[lb_k + 2][lb_n] = bv.z; Bs[lb_k + 3][lb_n] = bv.w;
        __syncthreads();
        #pragma unroll
        for (int kk = 0; kk < 16; ++kk) {
            float4 a = *(const float4*)&As[kk][ty << 2];
            float4 b = *(const float4*)&Bs[kk][tx << 2];
            float a4[4] = {a.x, a.y, a.z, a.w};
            float b4[4] = {b.x, b.y, b.z, b.w};
            #pragma unroll
            for (int i = 0; i < 4; ++i)
                #pragma unroll
                for (int jj = 0; jj < 4; ++jj)
                    acc[i][jj] = fmaf(a4[i], b4[jj], acc[i][jj]);
        }
    }
    #pragma unroll
    for (int i = 0; i < 4; ++i) {
        const int m = m0 + (ty << 2) + i;
        if (m >= M) continue;
        #pragma unroll
        for (int jj = 0; jj < 4; ++jj) {
            const int n = n0 + (tx << 2) + jj;
            if (n >= N) continue;
            float v = acc[i][jj];
            if (out_mode == 0) {
                if (bias) v += bias[n];
                out[(size_t)m * N + n] = v;
            } else {
                const int b = m & 15, t = m >> 4;
                out[(size_t)b * ((size_t)TDEC * N) + (size_t)t * N + n] = v + base[(size_t)b * N + n];
            }
        }
    }
}

// ------------- device-wide step barrier (monotonic counter, LLC-coherent) -------------
// All producer stores use RELAXED/AGENT atomics (sc0 sc1 -> bypass L1/L2, land at LLC).
// So no acquire/release cache maintenance is needed: drain vmcnt (stores at LLC),
// relaxed-add the flag, relaxed-poll. Per-wave in-order issue means post-barrier sc1
// loads are issued after the flag read observed the target -> they see peer stores.
// (The old ACQUIRE-per-poll version invalidated L2 every spin iteration: 28 us/step.)
__device__ __forceinline__ void step_barrier(unsigned* bar, unsigned target)
{
    __syncthreads();   // compiler emits s_waitcnt vmcnt(0) before s_barrier -> all waves' stores drained
    if (threadIdx.x == 0) {
        __builtin_amdgcn_s_waitcnt(0);  // belt-and-braces for this wave
        __hip_atomic_fetch_add(bar, 1u, __ATOMIC_RELAXED, __HIP_MEMORY_SCOPE_AGENT);
        while (__hip_atomic_load(bar, __ATOMIC_RELAXED, __HIP_MEMORY_SCOPE_AGENT) < target)
            __builtin_amdgcn_s_sleep(1);
    }
    __syncthreads();
}

// ---------------- persistent bidirectional encoder GRU recurrence ----------------
// 128 blocks: blocks [0,64) = forward, [64,128) = backward. Each block owns 8 hidden
// units (24 Whh rows) with weights in VGPRs (interleaved k: thread seg handles k = seg+16i).
// fwd and bwd use separate barrier counters (independent progress, fewer arrivals each).
__global__ __launch_bounds__(256) void enc_rec_kernel(
    const float* __restrict__ gi_f, const float* __restrict__ gi_b,
    const float* __restrict__ Whh_f, const float* __restrict__ Whh_b,
    const float* __restrict__ bhh_f, const float* __restrict__ bhh_b,
    float* __restrict__ enc_out,   // [16][256][1024]
    float* __restrict__ h_buf,     // [2 parity][2 dir][16][512]
    unsigned* __restrict__ bar)    // bar[0]=fwd, bar[64]=bwd (separate cache lines)
{
    const int dir  = blockIdx.x >> 6;
    const int ublk = blockIdx.x & 63;
    const float* gi  = dir ? gi_b  : gi_f;
    const float* Whh = dir ? Whh_b : Whh_f;
    const float* bhh = dir ? bhh_b : bhh_f;
    unsigned* mybar = bar + dir * 64;
    const int tid = threadIdx.x;
    const int u   = tid >> 5;        // 0..7 unit within block
    const int bh  = (tid >> 4) & 1;  // batch half
    const int seg = tid & 15;        // k segment
    const int j   = ublk * 8 + u;    // global hidden unit

    float w0[32], w1[32], w2[32];
    #pragma unroll
    for (int i = 0; i < 32; ++i) {
        const int k = seg + (i << 4);
        w0[i] = Whh[(size_t)(0 * HID + j) * HID + k];
        w1[i] = Whh[(size_t)(1 * HID + j) * HID + k];
        w2[i] = Whh[(size_t)(2 * HID + j) * HID + k];
    }
    __shared__ float hs[BATCH * HID];
    __shared__ float red[8][16][3];

    float* hb = h_buf + dir * (BATCH * HID);
    const int PST = 2 * BATCH * HID;

    for (int s = 0; s < SLEN; ++s) {
        const int par = s & 1;
        const int s_eff = dir ? (SLEN - 1 - s) : s;
        const float* hsrc = hb + par * PST;
        for (int i = tid; i < BATCH * HID; i += 256)
            hs[i] = __hip_atomic_load(hsrc + i, __ATOMIC_RELAXED, __HIP_MEMORY_SCOPE_AGENT);
        __syncthreads();

        float a0[8] = {}, a1[8] = {}, a2[8] = {};
        #pragma unroll
        for (int i = 0; i < 32; ++i) {
            const int k = seg + (i << 4);
            const float* hp = hs + bh * (8 * HID) + k;
            #pragma unroll
            for (int b2 = 0; b2 < 8; ++b2) {
                const float hv = hp[b2 * HID];
                a0[b2] = fmaf(w0[i], hv, a0[b2]);
                a1[b2] = fmaf(w1[i], hv, a1[b2]);
                a2[b2] = fmaf(w2[i], hv, a2[b2]);
            }
        }
        #pragma unroll
        for (int off = 1; off < 16; off <<= 1) {
            #pragma unroll
            for (int b2 = 0; b2 < 8; ++b2) {
                a0[b2] += __shfl_xor(a0[b2], off, 64);
                a1[b2] += __shfl_xor(a1[b2], off, 64);
                a2[b2] += __shfl_xor(a2[b2], off, 64);
            }
        }
        if (seg == 0) {
            #pragma unroll
            for (int b2 = 0; b2 < 8; ++b2) {
                const int b = bh * 8 + b2;
                red[u][b][0] = a0[b2];
                red[u][b][1] = a1[b2];
                red[u][b][2] = a2[b2];
            }
        }
        __syncthreads();
        if (tid < 128) {
            const int u2 = tid >> 4, b = tid & 15;
            const int jj = ublk * 8 + u2;
            const float ghr = red[u2][b][0] + bhh[jj];
            const float ghz = red[u2][b][1] + bhh[HID + jj];
            const float ghn = red[u2][b][2] + bhh[2 * HID + jj];
            const float* gp = gi + (size_t)(b * SLEN + s_eff) * 1536;
            const float r = sigmoidf_(gp[jj] + ghr);
            const float z = sigmoidf_(gp[HID + jj] + ghz);
            const float n = tanhf(gp[2 * HID + jj] + r * ghn);
            const float hnew = (1.f - z) * n + z * hs[b * HID + jj];
            enc_out[(size_t)(b * SLEN + s_eff) * 1024 + dir * HID + jj] = hnew;
            __hip_atomic_store(hb + (par ^ 1) * PST + b * HID + jj, hnew,
                               __ATOMIC_RELAXED, __HIP_MEMORY_SCOPE_AGENT);
        }
        step_barrier(mybar, 64u * (unsigned)(s + 1));
    }
}

// ---------------- persistent decoder GRU recurrence (64 blocks) ----------------
__global__ __launch_bounds__(256) void dec_rec_kernel(
    const float* __restrict__ gi_x,   // [99*16][1536] (includes dec_bih), m = t*16+b
    const float* __restrict__ gi_ctx, // [16][1536]
    const float* __restrict__ Whh, const float* __restrict__ bhh,
    const float* __restrict__ h_init, // [16][512]
    float* __restrict__ h_all,        // [99][16][512]
    unsigned* __restrict__ bar)
{
    const int ublk = blockIdx.x;
    const int tid = threadIdx.x;
    const int u   = tid >> 5;
    const int bh  = (tid >> 4) & 1;
    const int seg = tid & 15;
    const int j   = ublk * 8 + u;

    float w0[32], w1[32], w2[32];
    #pragma unroll
    for (int i = 0; i < 32; ++i) {
        const int k = seg + (i << 4);
        w0[i] = Whh[(size_t)(0 * HID + j) * HID + k];
        w1[i] = Whh[(size_t)(1 * HID + j) * HID + k];
        w2[i] = Whh[(size_t)(2 * HID + j) * HID + k];
    }
    __shared__ float hs[BATCH * HID];
    __shared__ float red[8][16][3];

    for (int t = 0; t < TDEC; ++t) {
        const float* hsrc = (t == 0) ? h_init : (h_all + (size_t)(t - 1) * (BATCH * HID));
        for (int i = tid; i < BATCH * HID; i += 256)
            hs[i] = __hip_atomic_load(hsrc + i, __ATOMIC_RELAXED, __HIP_MEMORY_SCOPE_AGENT);
        __syncthreads();

        float a0[8] = {}, a1[8] = {}, a2[8] = {};
        #pragma unroll
        for (int i = 0; i < 32; ++i) {
            const int k = seg + (i << 4);
            const float* hp = hs + bh * (8 * HID) + k;
            #pragma unroll
            for (int b2 = 0; b2 < 8; ++b2) {
                const float hv = hp[b2 * HID];
                a0[b2] = fmaf(w0[i], hv, a0[b2]);
                a1[b2] = fmaf(w1[i], hv, a1[b2]);
                a2[b2] = fmaf(w2[i], hv, a2[b2]);
            }
        }
        #pragma unroll
        for (int off = 1; off < 16; off <<= 1) {
            #pragma unroll
            for (int b2 = 0; b2 < 8; ++b2) {
                a0[b2] += __shfl_xor(a0[b2], off, 64);
                a1[b2] += __shfl_xor(a1[b2], off, 64);
                a2[b2] += __shfl_xor(a2[b2], off, 64);
            }
        }
        if (seg == 0) {
            #pragma unroll
            for (int b2 = 0; b2 < 8; ++b2) {
                const int b = bh * 8 + b2;
                red[u][b][0] = a0[b2];
                red[u][b][1] = a1[b2];
                red[u][b][2] = a2[b2];
            }
        }
        __syncthreads();
        if (tid < 128) {
            const int u2 = tid >> 4, b = tid & 15;
            const int jj = ublk * 8 + u2;
            const float ghr = red[u2][b][0] + bhh[jj];
            const float ghz = red[u2][b][1] + bhh[HID + jj];
            const float ghn = red[u2][b][2] + bhh[2 * HID + jj];
            const float* gxp = gi_x + (size_t)(t * BATCH + b) * 1536;
            const float* gcp = gi_ctx + (size_t)b * 1536;
            const float r = sigmoidf_(gxp[jj] + gcp[jj] + ghr);
            const float z = sigmoidf_(gxp[HID + jj] + gcp[HID + jj] + ghz);
            const float n = tanhf(gxp[2 * HID + jj] + gcp[2 * HID + jj] + r * ghn);
            const float hnew = (1.f - z) * n + z * hs[b * HID + jj];
            __hip_atomic_store(h_all + (size_t)t * (BATCH * HID) + b * HID + jj, hnew,
                               __ATOMIC_RELAXED, __HIP_MEMORY_SCOPE_AGENT);
        }
        step_barrier(bar, (unsigned)DEC_BLOCKS * (unsigned)(t + 1));
    }
}

// ---------------- attention precompute kernels ----------------
// cw[m] = sum_j comb_W[j] * attn_W[j, m], m < 1024  (enc_out part of the score;
// the h-dependent part is constant across s and cancels in softmax)
__global__ __launch_bounds__(256) void cw_kernel(const float* __restrict__ attnW,
                                                 const float* __restrict__ combW,
                                                 float* __restrict__ cw)
{
    const int m = blockIdx.x * 256 + threadIdx.x;
    if (m < 1024) {
        float s = 0.f;
        for (int jj = 0; jj < HID; ++jj)
            s = fmaf(combW[jj], attnW[(size_t)jj * 1536 + m], s);
        cw[m] = s;
    }
}

__global__ __launch_bounds__(256) void score_kernel(const float* __restrict__ enc_out,
                                                    const float* __restrict__ cw,
                                                    float* __restrict__ score)
{
    const int g = blockIdx.x * 256 + threadIdx.x;
    const int wv = g >> 6, lane = g & 63;   // wv = b*256+s, 4096 waves total
    const float* e = enc_out + (size_t)wv * 1024;
    float s = 0.f;
    #pragma unroll
    for (int i = 0; i < 16; ++i) {
        const int idx = i * 64 + lane;
        s = fmaf(cw[idx], e[idx], s);
    }
    #pragma unroll
    for (int off = 32; off; off >>= 1) s += __shfl_xor(s, off, 64);
    if (lane == 0) score[wv] = s;
}

__global__ __launch_bounds__(256) void attn_kernel(const float* __restrict__ enc_out,
                                                   const float* __restrict__ score,
                                                   const int* __restrict__ mask,
                                                   float* __restrict__ ctx0,
                                                   float* __restrict__ validv)
{
    const int b = blockIdx.x, t = threadIdx.x;   // t = s position, block = batch
    __shared__ float wsm[SLEN];
    __shared__ float rb[32];
    const int mk = mask[b * SLEN + t];
    const float sc = (mk > 0) ? score[b * SLEN + t] : -1e9f;
    float mx = sc;
    #pragma unroll
    for (int off = 32; off; off >>= 1) mx = fmaxf(mx, __shfl_xor(mx, off, 64));
    if ((t & 63) == 0) rb[t >> 6] = mx;
    __syncthreads();
    const float m4 = fmaxf(fmaxf(rb[0], rb[1]), fmaxf(rb[2], rb[3]));
    const float e = expf(sc - m4);   // masked: exp(-1e9-...) underflows to exactly 0
    float sm = e;
    #pragma unroll
    for (int off = 32; off; off >>= 1) sm += __shfl_xor(sm, off, 64);
    if ((t & 63) == 0) rb[8 + (t >> 6)] = sm;
    float vm = (float)mk;
    #pragma unroll
    for (int off = 32; off; off >>= 1) vm += __shfl_xor(vm, off, 64);
    if ((t & 63) == 0) rb[16 + (t >> 6)] = vm;
    __syncthreads();
    const float tot = rb[8] + rb[9] + rb[10] + rb[11];
    wsm[t] = e / tot;
    if (t == 0) validv[b] = rb[16] + rb[17] + rb[18] + rb[19];
    __syncthreads();
    for (int d = t; d < 1024; d += 256) {
        float acc = 0.f;
        for (int s = 0; s < SLEN; ++s)
            acc = fmaf(wsm[s], enc_out[(size_t)(b * SLEN + s) * 1024 + d], acc);
        ctx0[b * 1024 + d] = acc;
    }
}

__global__ __launch_bounds__(256) void hinit_kernel(const float* __restrict__ enc_out,
                                                    float* __restrict__ h_init)
{
    const int i = blockIdx.x * 256 + threadIdx.x;  // 0..8191
    const int b = i >> 9, jj = i & 511;
    h_init[i] = enc_out[(size_t)(b * SLEN + (SLEN - 1)) * 1024 + jj]
              + enc_out[(size_t)(b * SLEN + 0) * 1024 + HID + jj];
}

__global__ __launch_bounds__(256) void ctxp_kernel(const float* __restrict__ ctx0,
                                                   const float* __restrict__ projW,
                                                   const float* __restrict__ projb,
                                                   const float* __restrict__ validv,
                                                   float* __restrict__ ctxp)
{
    const int i = blockIdx.x * 256 + threadIdx.x;  // 0..8191: b*512+n
    const int b = i >> 9, n = i & 511;
    const float* c = ctx0 + (size_t)b * 1024;
    const float* w = projW + (size_t)n * 1024;
    float s = projb[n];
    for (int k = 0; k < 1024; k += 4) {
        const float4 cv = *(const float4*)(c + k);
        const float4 wv = *(const float4*)(w + k);
        s = fmaf(cv.x, wv.x, s); s = fmaf(cv.y, wv.y, s);
        s = fmaf(cv.z, wv.z, s); s = fmaf(cv.w, wv.w, s);
    }
    ctxp[i] = (validv[b] > 0.f) ? s : 0.f;
}

__global__ __launch_bounds__(256) void gictx_kernel(const float* __restrict__ ctxp,
                                                    const float* __restrict__ dWih,
                                                    float* __restrict__ gi_ctx)
{
    const int i = blockIdx.x * 256 + threadIdx.x;  // 0..24575: b*1536+r
    const int b = i / 1536, r = i % 1536;
    const float* c = ctxp + (size_t)b * HID;
    const float* w = dWih + (size_t)r * 1280 + 768;  // ctx columns of dec_Wih
    float s = 0.f;
    for (int k = 0; k < HID; k += 4) {
        const float4 cv = *(const float4*)(c + k);
        const float4 wv = *(const float4*)(w + k);
        s = fmaf(cv.x, wv.x, s); s = fmaf(cv.y, wv.y, s);
        s = fmaf(cv.z, wv.z, s); s = fmaf(cv.w, wv.w, s);
    }
    gi_ctx[i] = s;
}

extern "C" void kernel_launch(void* const* d_in, const int* in_sizes, int n_in,
                              void* d_out, int out_size, void* d_ws, size_t ws_size,
                              hipStream_t stream)
{
    const float* bert  = (const float*)d_in[0];
    const int*   amask = (const int*)d_in[1];
    const int*   ids   = (const int*)d_in[2];
    const float* emb   = (const float*)d_in[3];
    const float* eWihf = (const float*)d_in[4];
    const float* eWhhf = (const float*)d_in[5];
    const float* ebihf = (const float*)d_in[6];
    const float* ebhhf = (const float*)d_in[7];
    const float* eWihb = (const float*)d_in[8];
    const float* eWhhb = (const float*)d_in[9];
    const float* ebihb = (const float*)d_in[10];
    const float* ebhhb = (const float*)d_in[11];
    const float* dWih  = (const float*)d_in[12];
    const float* dWhh  = (const float*)d_in[13];
    const float* dbih  = (const float*)d_in[14];
    const float* dbhh  = (const float*)d_in[15];
    const float* attnW = (const float*)d_in[16];
    const float* combW = (const float*)d_in[18];
    const float* projW = (const float*)d_in[20];
    const float* projb = (const float*)d_in[21];
    const float* outW  = (const float*)d_in[22];
    const float* outb  = (const float*)d_in[23];
    float* out = (float*)d_out;

    float* ws = (float*)d_ws;
    size_t off = 0;
    auto alloc = [&](size_t n) { float* p = ws + off; off += (n + 255) & ~(size_t)255; return p; };
    float* h_buf   = alloc(2 * 2 * BATCH * HID);          // 32768 (must be first, memset)
    float* barf    = alloc(256);                          // barrier counters: [0]=encF,[64]=encB,[128]=dec
    unsigned* bar  = (unsigned*)barf;
    float* cw      = alloc(1024);
    float* score   = alloc(BATCH * SLEN);
    float* validv  = alloc(BATCH);
    float* ctx0    = alloc(BATCH * 1024);
    float* ctxp    = alloc(BATCH * HID);
    float* h_init  = alloc(BATCH * HID);
    float* gi_ctx  = alloc(BATCH * 1536);
    float* gi_f    = alloc((size_t)BATCH * SLEN * 1536);
    float* gi_b    = alloc((size_t)BATCH * SLEN * 1536);
    float* enc_out = alloc((size_t)BATCH * SLEN * 1024);
    float* gi_x    = alloc((size_t)TDEC * BATCH * 1536);
    float* basel   = alloc((size_t)BATCH * VOC);
    float* h_all   = alloc((size_t)TDEC * BATCH * HID);

    // zero h0 and barrier counters (ws is poisoned 0xAA before every launch)
    hipMemsetAsync(h_buf, 0, (2 * 2 * BATCH * HID + 256) * sizeof(float), stream);

    const dim3 blk(256);
    // encoder input projections gi = x @ Wih^T + bih, layout [b][s][1536]
    gemm_k<<<dim3(1536 / 64, (BATCH * SLEN) / 64), blk, 0, stream>>>(
        bert, EMB, eWihf, EMB, ebihf, nullptr, gi_f, BATCH * SLEN, 1536, EMB, nullptr, 0);
    gemm_k<<<dim3(1536 / 64, (BATCH * SLEN) / 64), blk, 0, stream>>>(
        bert, EMB, eWihb, EMB, ebihb, nullptr, gi_b, BATCH * SLEN, 1536, EMB, nullptr, 0);
    cw_kernel<<<4, blk, 0, stream>>>(attnW, combW, cw);
    // bidirectional recurrence
    enc_rec_kernel<<<ENC_BLOCKS, blk, 0, stream>>>(gi_f, gi_b, eWhhf, eWhhb, ebhhf, ebhhb,
                                                   enc_out, h_buf, bar);
    // attention (h-independent): scores -> softmax -> ctx -> proj
    score_kernel<<<1024, blk, 0, stream>>>(enc_out, cw, score);
    attn_kernel<<<BATCH, blk, 0, stream>>>(enc_out, score, amask, ctx0, validv);
    hinit_kernel<<<32, blk, 0, stream>>>(enc_out, h_init);
    ctxp_kernel<<<32, blk, 0, stream>>>(ctx0, projW, projb, validv, ctxp);
    gictx_kernel<<<96, blk, 0, stream>>>(ctxp, dWih, gi_ctx);
    // token-embedding projection (gather GEMM), m = t*16+b
    gemm_k<<<dim3(1536 / 64, (TDEC * BATCH + 63) / 64), blk, 0, stream>>>(
        emb, EMB, dWih, 1280, dbih, nullptr, gi_x, TDEC * BATCH, 1536, EMB, ids, 0);
    // base logits = ctxp @ outW[:,512:]^T + out_b
    gemm_k<<<dim3((VOC + 63) / 64, 1), blk, 0, stream>>>(
        ctxp, HID, outW + HID, 1024, outb, nullptr, basel, BATCH, VOC, HID, nullptr, 0);
    // decoder recurrence -> h_all
    dec_rec_kernel<<<DEC_BLOCKS, blk, 0, stream>>>(gi_x, gi_ctx, dWhh, dbhh, h_init, h_all, bar + 128);
    // final logits = h_all @ outW[:,0:512]^T + base, scattered to [b][t][v]
    gemm_k<<<dim3((VOC + 63) / 64, (TDEC * BATCH + 63) / 64), blk, 0, stream>>>(
        h_all, HID, outW, 1024, nullptr, basel, out, TDEC * BATCH, VOC, HID, nullptr, 1);
}

// Round 3
// 4996.702 us; speedup vs baseline: 2.1834x; 1.3821x over previous
//
#include <hip/hip_runtime.h>

#define BATCH 16
#define SLEN 256
#define HID 512
#define EMB 768
#define VOC 30522
#define TDEC 99
#define ENC_BLOCKS 128
#define DEC_BLOCKS 64

typedef unsigned long long ull;

__device__ __forceinline__ float sigmoidf_(float x) { return 1.f / (1.f + expf(-x)); }

// ---------------- generic tiled fp32 GEMM: C = A @ W^T (+bias/base) ----------------
__global__ __launch_bounds__(256) void gemm_k(
    const float* __restrict__ A, int lda,
    const float* __restrict__ W, int ldb,
    const float* __restrict__ bias,
    const float* __restrict__ base,
    float* __restrict__ out,
    int M, int N, int K,
    const int* __restrict__ ids,
    int out_mode)
{
    __shared__ float As[16][64];
    __shared__ float Bs[16][64];
    const int tid = threadIdx.x;
    const int m0 = blockIdx.y * 64, n0 = blockIdx.x * 64;
    const int la_m = tid >> 2, la_k = (tid & 3) << 2;
    const int lb_n = la_m,    lb_k = la_k;
    const int tx = tid & 15, ty = tid >> 4;

    const int gm = m0 + la_m;
    const bool a_ok = gm < M;
    const float* Ap = A;
    if (a_ok) {
        int r = gm;
        if (ids) r = ids[(gm & 15) * 100 + (gm >> 4)];
        Ap = A + (size_t)r * lda;
    }
    const int gn = n0 + lb_n;
    const bool b_ok = gn < N;
    const float* Wp = b_ok ? (W + (size_t)gn * ldb) : W;

    float acc[4][4] = {};
    for (int k0 = 0; k0 < K; k0 += 16) {
        float4 av = make_float4(0.f, 0.f, 0.f, 0.f);
        float4 bv = make_float4(0.f, 0.f, 0.f, 0.f);
        if (a_ok) av = *(const float4*)(Ap + k0 + la_k);
        if (b_ok) bv = *(const float4*)(Wp + k0 + lb_k);
        __syncthreads();
        As[la_k + 0][la_m] = av.x; As[la_k + 1][la_m] = av.y;
        As[la_k + 2][la_m] = av.z; As[la_k + 3][la_m] = av.w;
        Bs[lb_k + 0][lb_n] = bv.x; Bs[lb_k + 1][lb_n] = bv.y;
        Bs[lb_k + 2][lb_n] = bv.z; Bs[lb_k + 3][lb_n] = bv.w;
        __syncthreads();
        #pragma unroll
        for (int kk = 0; kk < 16; ++kk) {
            float4 a = *(const float4*)&As[kk][ty << 2];
            float4 b = *(const float4*)&Bs[kk][tx << 2];
            float a4[4] = {a.x, a.y, a.z, a.w};
            float b4[4] = {b.x, b.y, b.z, b.w};
            #pragma unroll
            for (int i = 0; i < 4; ++i)
                #pragma unroll
                for (int jj = 0; jj < 4; ++jj)
                    acc[i][jj] = fmaf(a4[i], b4[jj], acc[i][jj]);
        }
    }
    #pragma unroll
    for (int i = 0; i < 4; ++i) {
        const int m = m0 + (ty << 2) + i;
        if (m >= M) continue;
        #pragma unroll
        for (int jj = 0; jj < 4; ++jj) {
            const int n = n0 + (tx << 2) + jj;
            if (n >= N) continue;
            float v = acc[i][jj];
            if (out_mode == 0) {
                if (bias) v += bias[n];
                out[(size_t)m * N + n] = v;
            } else {
                const int b = m & 15, t = m >> 4;
                out[(size_t)b * ((size_t)TDEC * N) + (size_t)t * N + n] = v + base[(size_t)b * N + n];
            }
        }
    }
}

// ------------- device-wide step barrier: 8 counter slots, 128B apart -------------
// All h-exchange uses relaxed AGENT atomics (LLC-coherent, bypass L1/L2) so no
// acquire/release cache maintenance needed. Arrivals spread over 8 LLC lines to
// cut atomic serialization; waiter sums all 8 (monotonic counters -> sum can only
// under-count, never falsely exceed the per-step target).
__device__ __forceinline__ void step_barrier(unsigned* base, int slot, unsigned target)
{
    __syncthreads();   // drains each wave's vmcnt before s_barrier
    if (threadIdx.x == 0) {
        __builtin_amdgcn_s_waitcnt(0);
        __hip_atomic_fetch_add(base + slot * 32, 1u, __ATOMIC_RELAXED, __HIP_MEMORY_SCOPE_AGENT);
        for (;;) {
            unsigned sum = 0;
            #pragma unroll
            for (int q = 0; q < 8; ++q)
                sum += __hip_atomic_load(base + q * 32, __ATOMIC_RELAXED, __HIP_MEMORY_SCOPE_AGENT);
            if (sum >= target) break;
            __builtin_amdgcn_s_sleep(1);
        }
    }
    __syncthreads();
}

// ---------------- persistent bidirectional encoder GRU recurrence ----------------
// 64 blocks/dir, 8 hidden units each. Thread (u,bh,seg) holds Whh[3][j][k] for
// k in {i*64+seg*4+c} (contiguous quads -> ds_read_b128 conflict-free h reads).
__global__ __launch_bounds__(256) void enc_rec_kernel(
    const float* __restrict__ gi_f, const float* __restrict__ gi_b,
    const float* __restrict__ Whh_f, const float* __restrict__ Whh_b,
    const float* __restrict__ bhh_f, const float* __restrict__ bhh_b,
    float* __restrict__ enc_out,   // [16][256][1024]
    float* __restrict__ h_buf,     // [2 parity][2 dir][16][512]
    unsigned* __restrict__ bar)    // [dir*256 + slot*32]
{
    const int dir  = blockIdx.x >> 6;
    const int ublk = blockIdx.x & 63;
    const float* gi  = dir ? gi_b  : gi_f;
    const float* Whh = dir ? Whh_b : Whh_f;
    const float* bhh = dir ? bhh_b : bhh_f;
    unsigned* mybar = bar + dir * 256;
    const int slot = ublk & 7;
    const int tid = threadIdx.x;
    const int u   = tid >> 5;        // unit within block (compute phase)
    const int bh  = (tid >> 4) & 1;  // batch half
    const int seg = tid & 15;        // k quad-segment
    const int j   = ublk * 8 + u;

    float4 w0q[8], w1q[8], w2q[8];
    #pragma unroll
    for (int i = 0; i < 8; ++i) {
        const int k = i * 64 + seg * 4;
        w0q[i] = *(const float4*)&Whh[(size_t)(0 * HID + j) * HID + k];
        w1q[i] = *(const float4*)&Whh[(size_t)(1 * HID + j) * HID + k];
        w2q[i] = *(const float4*)&Whh[(size_t)(2 * HID + j) * HID + k];
    }
    // gate-phase mapping (tid<128): consecutive lanes -> consecutive hidden units
    const int u2 = tid & 7, gb = (tid >> 3) & 15;
    const int jj = ublk * 8 + u2;
    const float bv0 = bhh[jj], bv1 = bhh[HID + jj], bv2 = bhh[2 * HID + jj];

    __shared__ float hs[BATCH * HID];
    __shared__ float red[8][16][3];

    float* hb = h_buf + dir * (BATCH * HID);
    const int PST = 2 * BATCH * HID;

    for (int s = 0; s < SLEN; ++s) {
        const int par = s & 1;
        const int s_eff = dir ? (SLEN - 1 - s) : s;

        // prefetch gi for this step (h-independent; hides HBM latency)
        float gi0 = 0.f, gi1 = 0.f, gi2 = 0.f;
        if (tid < 128) {
            const float* gp = gi + (size_t)(gb * SLEN + s_eff) * 1536;
            gi0 = gp[jj]; gi1 = gp[HID + jj]; gi2 = gp[2 * HID + jj];
        }

        // broadcast h: 16 x b64 LLC-coherent loads per thread -> LDS
        const ull* hsrc = (const ull*)(hb + par * PST);
        #pragma unroll
        for (int it = 0; it < 16; ++it) {
            ull v = __hip_atomic_load(hsrc + tid + it * 256, __ATOMIC_RELAXED, __HIP_MEMORY_SCOPE_AGENT);
            ((ull*)hs)[tid + it * 256] = v;
        }
        __syncthreads();

        float a0[8] = {}, a1[8] = {}, a2[8] = {};
        #pragma unroll
        for (int i = 0; i < 8; ++i) {
            #pragma unroll
            for (int b2 = 0; b2 < 8; ++b2) {
                const float4 hq = *(const float4*)&hs[(bh * 8 + b2) * HID + i * 64 + seg * 4];
                a0[b2] = fmaf(w0q[i].x, hq.x, fmaf(w0q[i].y, hq.y, fmaf(w0q[i].z, hq.z, fmaf(w0q[i].w, hq.w, a0[b2]))));
                a1[b2] = fmaf(w1q[i].x, hq.x, fmaf(w1q[i].y, hq.y, fmaf(w1q[i].z, hq.z, fmaf(w1q[i].w, hq.w, a1[b2]))));
                a2[b2] = fmaf(w2q[i].x, hq.x, fmaf(w2q[i].y, hq.y, fmaf(w2q[i].z, hq.z, fmaf(w2q[i].w, hq.w, a2[b2]))));
            }
        }
        #pragma unroll
        for (int off = 1; off < 16; off <<= 1) {
            #pragma unroll
            for (int b2 = 0; b2 < 8; ++b2) {
                a0[b2] += __shfl_xor(a0[b2], off, 64);
                a1[b2] += __shfl_xor(a1[b2], off, 64);
                a2[b2] += __shfl_xor(a2[b2], off, 64);
            }
        }
        if (seg == 0) {
            #pragma unroll
            for (int b2 = 0; b2 < 8; ++b2) {
                const int b = bh * 8 + b2;
                red[u][b][0] = a0[b2];
                red[u][b][1] = a1[b2];
                red[u][b][2] = a2[b2];
            }
        }
        __syncthreads();
        if (tid < 128) {
            const float ghr = red[u2][gb][0] + bv0;
            const float ghz = red[u2][gb][1] + bv1;
            const float ghn = red[u2][gb][2] + bv2;
            const float r = sigmoidf_(gi0 + ghr);
            const float z = sigmoidf_(gi1 + ghz);
            const float n = tanhf(gi2 + r * ghn);
            const float hnew = (1.f - z) * n + z * hs[gb * HID + jj];
            enc_out[(size_t)(gb * SLEN + s_eff) * 1024 + dir * HID + jj] = hnew;
            __hip_atomic_store(hb + (par ^ 1) * PST + gb * HID + jj, hnew,
                               __ATOMIC_RELAXED, __HIP_MEMORY_SCOPE_AGENT);
        }
        step_barrier(mybar, slot, 64u * (unsigned)(s + 1));
    }
}

// ---------------- persistent decoder GRU recurrence (64 blocks) ----------------
__global__ __launch_bounds__(256) void dec_rec_kernel(
    const float* __restrict__ gi_x,   // [99*16][1536] (includes dec_bih), m = t*16+b
    const float* __restrict__ gi_ctx, // [16][1536]
    const float* __restrict__ Whh, const float* __restrict__ bhh,
    const float* __restrict__ h_init, // [16][512]
    float* __restrict__ h_all,        // [99][16][512]
    unsigned* __restrict__ bar)
{
    const int ublk = blockIdx.x;
    const int slot = ublk & 7;
    const int tid = threadIdx.x;
    const int u   = tid >> 5;
    const int bh  = (tid >> 4) & 1;
    const int seg = tid & 15;
    const int j   = ublk * 8 + u;

    float4 w0q[8], w1q[8], w2q[8];
    #pragma unroll
    for (int i = 0; i < 8; ++i) {
        const int k = i * 64 + seg * 4;
        w0q[i] = *(const float4*)&Whh[(size_t)(0 * HID + j) * HID + k];
        w1q[i] = *(const float4*)&Whh[(size_t)(1 * HID + j) * HID + k];
        w2q[i] = *(const float4*)&Whh[(size_t)(2 * HID + j) * HID + k];
    }
    const int u2 = tid & 7, gb = (tid >> 3) & 15;
    const int jj = ublk * 8 + u2;
    const float bv0 = bhh[jj], bv1 = bhh[HID + jj], bv2 = bhh[2 * HID + jj];
    // gi_ctx is step-invariant: hoist
    const float* gcp = gi_ctx + (size_t)gb * 1536;
    const float gc0 = gcp[jj], gc1 = gcp[HID + jj], gc2 = gcp[2 * HID + jj];

    __shared__ float hs[BATCH * HID];
    __shared__ float red[8][16][3];

    for (int t = 0; t < TDEC; ++t) {
        float gi0 = 0.f, gi1 = 0.f, gi2 = 0.f;
        if (tid < 128) {
            const float* gxp = gi_x + (size_t)(t * BATCH + gb) * 1536;
            gi0 = gxp[jj]; gi1 = gxp[HID + jj]; gi2 = gxp[2 * HID + jj];
        }
        const ull* hsrc = (const ull*)((t == 0) ? h_init : (h_all + (size_t)(t - 1) * (BATCH * HID)));
        #pragma unroll
        for (int it = 0; it < 16; ++it) {
            ull v = __hip_atomic_load(hsrc + tid + it * 256, __ATOMIC_RELAXED, __HIP_MEMORY_SCOPE_AGENT);
            ((ull*)hs)[tid + it * 256] = v;
        }
        __syncthreads();

        float a0[8] = {}, a1[8] = {}, a2[8] = {};
        #pragma unroll
        for (int i = 0; i < 8; ++i) {
            #pragma unroll
            for (int b2 = 0; b2 < 8; ++b2) {
                const float4 hq = *(const float4*)&hs[(bh * 8 + b2) * HID + i * 64 + seg * 4];
                a0[b2] = fmaf(w0q[i].x, hq.x, fmaf(w0q[i].y, hq.y, fmaf(w0q[i].z, hq.z, fmaf(w0q[i].w, hq.w, a0[b2]))));
                a1[b2] = fmaf(w1q[i].x, hq.x, fmaf(w1q[i].y, hq.y, fmaf(w1q[i].z, hq.z, fmaf(w1q[i].w, hq.w, a1[b2]))));
                a2[b2] = fmaf(w2q[i].x, hq.x, fmaf(w2q[i].y, hq.y, fmaf(w2q[i].z, hq.z, fmaf(w2q[i].w, hq.w, a2[b2]))));
            }
        }
        #pragma unroll
        for (int off = 1; off < 16; off <<= 1) {
            #pragma unroll
            for (int b2 = 0; b2 < 8; ++b2) {
                a0[b2] += __shfl_xor(a0[b2], off, 64);
                a1[b2] += __shfl_xor(a1[b2], off, 64);
                a2[b2] += __shfl_xor(a2[b2], off, 64);
            }
        }
        if (seg == 0) {
            #pragma unroll
            for (int b2 = 0; b2 < 8; ++b2) {
                const int b = bh * 8 + b2;
                red[u][b][0] = a0[b2];
                red[u][b][1] = a1[b2];
                red[u][b][2] = a2[b2];
            }
        }
        __syncthreads();
        if (tid < 128) {
            const float ghr = red[u2][gb][0] + bv0;
            const float ghz = red[u2][gb][1] + bv1;
            const float ghn = red[u2][gb][2] + bv2;
            const float r = sigmoidf_(gi0 + gc0 + ghr);
            const float z = sigmoidf_(gi1 + gc1 + ghz);
            const float n = tanhf(gi2 + gc2 + r * ghn);
            const float hnew = (1.f - z) * n + z * hs[gb * HID + jj];
            __hip_atomic_store(h_all + (size_t)t * (BATCH * HID) + gb * HID + jj, hnew,
                               __ATOMIC_RELAXED, __HIP_MEMORY_SCOPE_AGENT);
        }
        step_barrier(bar, slot, 64u * (unsigned)(t + 1));
    }
}

// ---------------- attention precompute kernels ----------------
__global__ __launch_bounds__(256) void cw_kernel(const float* __restrict__ attnW,
                                                 const float* __restrict__ combW,
                                                 float* __restrict__ cw)
{
    const int m = blockIdx.x * 256 + threadIdx.x;
    if (m < 1024) {
        float s = 0.f;
        for (int jj = 0; jj < HID; ++jj)
            s = fmaf(combW[jj], attnW[(size_t)jj * 1536 + m], s);
        cw[m] = s;
    }
}

__global__ __launch_bounds__(256) void score_kernel(const float* __restrict__ enc_out,
                                                    const float* __restrict__ cw,
                                                    float* __restrict__ score)
{
    const int g = blockIdx.x * 256 + threadIdx.x;
    const int wv = g >> 6, lane = g & 63;
    const float* e = enc_out + (size_t)wv * 1024;
    float s = 0.f;
    #pragma unroll
    for (int i = 0; i < 16; ++i) {
        const int idx = i * 64 + lane;
        s = fmaf(cw[idx], e[idx], s);
    }
    #pragma unroll
    for (int off = 32; off; off >>= 1) s += __shfl_xor(s, off, 64);
    if (lane == 0) score[wv] = s;
}

__global__ __launch_bounds__(256) void attn_kernel(const float* __restrict__ enc_out,
                                                   const float* __restrict__ score,
                                                   const int* __restrict__ mask,
                                                   float* __restrict__ ctx0,
                                                   float* __restrict__ validv)
{
    const int b = blockIdx.x, t = threadIdx.x;
    __shared__ float wsm[SLEN];
    __shared__ float rb[32];
    const int mk = mask[b * SLEN + t];
    const float sc = (mk > 0) ? score[b * SLEN + t] : -1e9f;
    float mx = sc;
    #pragma unroll
    for (int off = 32; off; off >>= 1) mx = fmaxf(mx, __shfl_xor(mx, off, 64));
    if ((t & 63) == 0) rb[t >> 6] = mx;
    __syncthreads();
    const float m4 = fmaxf(fmaxf(rb[0], rb[1]), fmaxf(rb[2], rb[3]));
    const float e = expf(sc - m4);
    float sm = e;
    #pragma unroll
    for (int off = 32; off; off >>= 1) sm += __shfl_xor(sm, off, 64);
    if ((t & 63) == 0) rb[8 + (t >> 6)] = sm;
    float vm = (float)mk;
    #pragma unroll
    for (int off = 32; off; off >>= 1) vm += __shfl_xor(vm, off, 64);
    if ((t & 63) == 0) rb[16 + (t >> 6)] = vm;
    __syncthreads();
    const float tot = rb[8] + rb[9] + rb[10] + rb[11];
    wsm[t] = e / tot;
    if (t == 0) validv[b] = rb[16] + rb[17] + rb[18] + rb[19];
    __syncthreads();
    for (int d = t; d < 1024; d += 256) {
        float acc = 0.f;
        for (int s = 0; s < SLEN; ++s)
            acc = fmaf(wsm[s], enc_out[(size_t)(b * SLEN + s) * 1024 + d], acc);
        ctx0[b * 1024 + d] = acc;
    }
}

__global__ __launch_bounds__(256) void hinit_kernel(const float* __restrict__ enc_out,
                                                    float* __restrict__ h_init)
{
    const int i = blockIdx.x * 256 + threadIdx.x;
    const int b = i >> 9, jj = i & 511;
    h_init[i] = enc_out[(size_t)(b * SLEN + (SLEN - 1)) * 1024 + jj]
              + enc_out[(size_t)(b * SLEN + 0) * 1024 + HID + jj];
}

__global__ __launch_bounds__(256) void ctxp_kernel(const float* __restrict__ ctx0,
                                                   const float* __restrict__ projW,
                                                   const float* __restrict__ projb,
                                                   const float* __restrict__ validv,
                                                   float* __restrict__ ctxp)
{
    const int i = blockIdx.x * 256 + threadIdx.x;
    const int b = i >> 9, n = i & 511;
    const float* c = ctx0 + (size_t)b * 1024;
    const float* w = projW + (size_t)n * 1024;
    float s = projb[n];
    for (int k = 0; k < 1024; k += 4) {
        const float4 cv = *(const float4*)(c + k);
        const float4 wv = *(const float4*)(w + k);
        s = fmaf(cv.x, wv.x, s); s = fmaf(cv.y, wv.y, s);
        s = fmaf(cv.z, wv.z, s); s = fmaf(cv.w, wv.w, s);
    }
    ctxp[i] = (validv[b] > 0.f) ? s : 0.f;
}

__global__ __launch_bounds__(256) void gictx_kernel(const float* __restrict__ ctxp,
                                                    const float* __restrict__ dWih,
                                                    float* __restrict__ gi_ctx)
{
    const int i = blockIdx.x * 256 + threadIdx.x;
    const int b = i / 1536, r = i % 1536;
    const float* c = ctxp + (size_t)b * HID;
    const float* w = dWih + (size_t)r * 1280 + 768;
    float s = 0.f;
    for (int k = 0; k < HID; k += 4) {
        const float4 cv = *(const float4*)(c + k);
        const float4 wv = *(const float4*)(w + k);
        s = fmaf(cv.x, wv.x, s); s = fmaf(cv.y, wv.y, s);
        s = fmaf(cv.z, wv.z, s); s = fmaf(cv.w, wv.w, s);
    }
    gi_ctx[i] = s;
}

extern "C" void kernel_launch(void* const* d_in, const int* in_sizes, int n_in,
                              void* d_out, int out_size, void* d_ws, size_t ws_size,
                              hipStream_t stream)
{
    const float* bert  = (const float*)d_in[0];
    const int*   amask = (const int*)d_in[1];
    const int*   ids   = (const int*)d_in[2];
    const float* emb   = (const float*)d_in[3];
    const float* eWihf = (const float*)d_in[4];
    const float* eWhhf = (const float*)d_in[5];
    const float* ebihf = (const float*)d_in[6];
    const float* ebhhf = (const float*)d_in[7];
    const float* eWihb = (const float*)d_in[8];
    const float* eWhhb = (const float*)d_in[9];
    const float* ebihb = (const float*)d_in[10];
    const float* ebhhb = (const float*)d_in[11];
    const float* dWih  = (const float*)d_in[12];
    const float* dWhh  = (const float*)d_in[13];
    const float* dbih  = (const float*)d_in[14];
    const float* dbhh  = (const float*)d_in[15];
    const float* attnW = (const float*)d_in[16];
    const float* combW = (const float*)d_in[18];
    const float* projW = (const float*)d_in[20];
    const float* projb = (const float*)d_in[21];
    const float* outW  = (const float*)d_in[22];
    const float* outb  = (const float*)d_in[23];
    float* out = (float*)d_out;

    float* ws = (float*)d_ws;
    size_t off = 0;
    auto alloc = [&](size_t n) { float* p = ws + off; off += (n + 255) & ~(size_t)255; return p; };
    float* h_buf   = alloc(2 * 2 * BATCH * HID);          // must be first (memset)
    float* barf    = alloc(1024);                         // barriers: encF @0, encB @256, dec @512
    unsigned* bar  = (unsigned*)barf;
    float* cw      = alloc(1024);
    float* score   = alloc(BATCH * SLEN);
    float* validv  = alloc(BATCH);
    float* ctx0    = alloc(BATCH * 1024);
    float* ctxp    = alloc(BATCH * HID);
    float* h_init  = alloc(BATCH * HID);
    float* gi_ctx  = alloc(BATCH * 1536);
    float* gi_f    = alloc((size_t)BATCH * SLEN * 1536);
    float* gi_b    = alloc((size_t)BATCH * SLEN * 1536);
    float* enc_out = alloc((size_t)BATCH * SLEN * 1024);
    float* gi_x    = alloc((size_t)TDEC * BATCH * 1536);
    float* basel   = alloc((size_t)BATCH * VOC);
    float* h_all   = alloc((size_t)TDEC * BATCH * HID);

    hipMemsetAsync(h_buf, 0, (2 * 2 * BATCH * HID + 1024) * sizeof(float), stream);

    const dim3 blk(256);
    gemm_k<<<dim3(1536 / 64, (BATCH * SLEN) / 64), blk, 0, stream>>>(
        bert, EMB, eWihf, EMB, ebihf, nullptr, gi_f, BATCH * SLEN, 1536, EMB, nullptr, 0);
    gemm_k<<<dim3(1536 / 64, (BATCH * SLEN) / 64), blk, 0, stream>>>(
        bert, EMB, eWihb, EMB, ebihb, nullptr, gi_b, BATCH * SLEN, 1536, EMB, nullptr, 0);
    cw_kernel<<<4, blk, 0, stream>>>(attnW, combW, cw);
    enc_rec_kernel<<<ENC_BLOCKS, blk, 0, stream>>>(gi_f, gi_b, eWhhf, eWhhb, ebhhf, ebhhb,
                                                   enc_out, h_buf, bar);
    score_kernel<<<1024, blk, 0, stream>>>(enc_out, cw, score);
    attn_kernel<<<BATCH, blk, 0, stream>>>(enc_out, score, amask, ctx0, validv);
    hinit_kernel<<<32, blk, 0, stream>>>(enc_out, h_init);
    ctxp_kernel<<<32, blk, 0, stream>>>(ctx0, projW, projb, validv, ctxp);
    gictx_kernel<<<96, blk, 0, stream>>>(ctxp, dWih, gi_ctx);
    gemm_k<<<dim3(1536 / 64, (TDEC * BATCH + 63) / 64), blk, 0, stream>>>(
        emb, EMB, dWih, 1280, dbih, nullptr, gi_x, TDEC * BATCH, 1536, EMB, ids, 0);
    gemm_k<<<dim3((VOC + 63) / 64, 1), blk, 0, stream>>>(
        ctxp, HID, outW + HID, 1024, outb, nullptr, basel, BATCH, VOC, HID, nullptr, 0);
    dec_rec_kernel<<<DEC_BLOCKS, blk, 0, stream>>>(gi_x, gi_ctx, dWhh, dbhh, h_init, h_all, bar + 512);
    gemm_k<<<dim3((VOC + 63) / 64, (TDEC * BATCH + 63) / 64), blk, 0, stream>>>(
        h_all, HID, outW, 1024, nullptr, basel, out, TDEC * BATCH, VOC, HID, nullptr, 1);
}